// Round 3
// baseline (1104.725 us; speedup 1.0000x reference)
//
#include <hip/hip_runtime.h>
#include <hip/hip_bf16.h>
#include <stdint.h>

#define HWSZ 16384
#define CCH 192
#define NB 8
#define NHEAD 4
#define DHEAD 48

typedef unsigned short u16;
typedef __bf16 bf16x8 __attribute__((ext_vector_type(8)));
typedef float f32x4 __attribute__((ext_vector_type(4)));
typedef short s16x8 __attribute__((ext_vector_type(8)));

__device__ __forceinline__ float b2f(u16 h){
  union { unsigned u; float f; } v; v.u = ((unsigned)h) << 16; return v.f;
}
__device__ __forceinline__ u16 f2b(float f){
  union { float f; unsigned u; } v; v.f = f;
  unsigned r = v.u + 0x7fffu + ((v.u >> 16) & 1u);
  return (u16)(r >> 16);
}

// ---------------------------------------------------------------------------
// K1: per-pixel LayerNorm over 192 channels (f32 in); writes normalized x
// TRANSPOSED as bf16 [b][hw][192] (K-contiguous rows for A*B^T MFMA GEMMs).
// ---------------------------------------------------------------------------
__global__ void k_ln_t(const float* __restrict__ x, const float* __restrict__ lnw,
                       const float* __restrict__ lnb, u16* __restrict__ out)
{
  __shared__ float xs[CCH * 65];        // [c][p] padded -> benign banks
  __shared__ float mus[64], rstds[64];
  __shared__ float lw[CCH], lb[CCH];
  int tid = threadIdx.x;
  int bx  = blockIdx.x;
  int b    = bx >> 8;                   // 256 tiles of 64 pixels per batch
  int tile = bx & 255;
  int p0   = tile * 64;
  if (tid < CCH){ lw[tid] = lnw[tid]; lb[tid] = lnb[tid]; }
  int pl = tid & 63, ch0 = tid >> 6;
  const float* xb = x + (size_t)b * CCH * HWSZ + p0 + pl;
  #pragma unroll
  for (int j = 0; j < 48; ++j){
    int c = ch0 + j * 4;
    xs[c * 65 + pl] = xb[(size_t)c * HWSZ];
  }
  __syncthreads();
  if (tid < 64){
    float s = 0.f, ss = 0.f;
    for (int c = 0; c < CCH; ++c){ float v = xs[c * 65 + tid]; s += v; ss += v * v; }
    float mu  = s * (1.f / CCH);
    float var = ss * (1.f / CCH) - mu * mu;
    mus[tid] = mu; rstds[tid] = rsqrtf(var + 1e-5f);
  }
  __syncthreads();
  u16* ob = out + ((size_t)b * HWSZ + p0) * CCH;   // contiguous 64*192 tile
  for (int i = 0; i < 48; ++i){
    int e = i * 256 + tid;
    int p = e / CCH, c = e - p * CCH;
    float v = (xs[c * 65 + p] - mus[p]) * rstds[p] * lw[c] + lb[c];
    ob[e] = f2b(v);
  }
}

// ---------------------------------------------------------------------------
// K2: MFMA GEMM  Out[b][o][n] = sum_c A[o][c] * Bm[b][n][c]   (A*B^T)
// A: f32 [192][192] row-major (converted to bf16 during LDS staging).
// Bm: bf16 [b][16384][192] row-major.
// Tile 64(M) x 128(N), whole K=192 in LDS (padded stride 200).
// F32OUT=1: add f32 residual and write f32 (final proj + q_in -> d_out).
// F32OUT=0: write bf16 intermediate.
// ---------------------------------------------------------------------------
template<int F32OUT>
__global__ __launch_bounds__(256, 2) void k_gemm(
    const float* __restrict__ A, const u16* __restrict__ Bm,
    void* __restrict__ Outv, const float* __restrict__ resid)
{
  __shared__ u16 lA[64 * 200];
  __shared__ u16 lB[128 * 200];
  int tid = threadIdx.x;
  int n0 = blockIdx.x * 128;
  int m0 = blockIdx.y * 64;
  int b  = blockIdx.z;
  {
    const float* ap = A + m0 * CCH;                     // 64*192 contiguous f32
    #pragma unroll
    for (int i = 0; i < 6; ++i){
      int off = (i * 256 + tid) * 8;
      float4 v0 = *(const float4*)(ap + off);
      float4 v1 = *(const float4*)(ap + off + 4);
      int row = off / CCH, col = off - row * CCH;
      s16x8 pk;
      pk[0] = (short)f2b(v0.x); pk[1] = (short)f2b(v0.y);
      pk[2] = (short)f2b(v0.z); pk[3] = (short)f2b(v0.w);
      pk[4] = (short)f2b(v1.x); pk[5] = (short)f2b(v1.y);
      pk[6] = (short)f2b(v1.z); pk[7] = (short)f2b(v1.w);
      *(s16x8*)(&lA[row * 200 + col]) = pk;
    }
  }
  {
    const u16* bp = Bm + ((size_t)b * HWSZ + n0) * CCH; // 128*192 contiguous
    #pragma unroll
    for (int i = 0; i < 12; ++i){
      int off = (i * 256 + tid) * 8;
      int4 v = *(const int4*)(bp + off);
      int row = off / CCH, col = off - row * CCH;
      *(int4*)(&lB[row * 200 + col]) = v;
    }
  }
  __syncthreads();
  int lane = tid & 63, wid = tid >> 6;
  int quad = lane >> 4, r = lane & 15;
  int wm = (wid >> 1) * 32, wn = (wid & 1) * 64;
  f32x4 acc[2][4] = {};
  #pragma unroll
  for (int k0 = 0; k0 < CCH; k0 += 32){
    bf16x8 af[2], bfr[4];
    #pragma unroll
    for (int i = 0; i < 2; ++i)
      af[i] = *(const bf16x8*)(&lA[(wm + i * 16 + r) * 200 + k0 + quad * 8]);
    #pragma unroll
    for (int j = 0; j < 4; ++j)
      bfr[j] = *(const bf16x8*)(&lB[(wn + j * 16 + r) * 200 + k0 + quad * 8]);
    #pragma unroll
    for (int i = 0; i < 2; ++i)
      #pragma unroll
      for (int j = 0; j < 4; ++j)
        acc[i][j] = __builtin_amdgcn_mfma_f32_16x16x32_bf16(af[i], bfr[j], acc[i][j], 0, 0, 0);
  }
  size_t obase = (size_t)b * CCH * HWSZ;
  #pragma unroll
  for (int i = 0; i < 2; ++i){
    #pragma unroll
    for (int rg = 0; rg < 4; ++rg){
      int o = m0 + wm + i * 16 + quad * 4 + rg;
      size_t rowb = obase + (size_t)o * HWSZ;
      #pragma unroll
      for (int j = 0; j < 4; ++j){
        int n = n0 + wn + j * 16 + r;
        float vv = acc[i][j][rg];
        if (F32OUT){
          ((float*)Outv)[rowb + n] = vv + resid[rowb + n];
        } else {
          ((u16*)Outv)[rowb + n] = f2b(vv);
        }
      }
    }
  }
}

// ---------------------------------------------------------------------------
// K3: depthwise 3x3, SAME padding, bf16 in/out, f32 weights; also accumulates
// per-(b,c) sum of squares (for fused L2-norm) via one atomic per wave.
// ---------------------------------------------------------------------------
__global__ void k_dw(const u16* __restrict__ in, const float* __restrict__ wd,
                     u16* __restrict__ out, float* __restrict__ ssq, int do_ssq)
{
  int tid = threadIdx.x;
  int bc  = blockIdx.x;                  // b*192 + c
  int c   = bc % CCH;
  float w[9];
  #pragma unroll
  for (int t = 0; t < 9; ++t) w[t] = wd[c * 9 + t];
  const u16* ip = in  + (size_t)bc * HWSZ;
  u16*       op = out + (size_t)bc * HWSZ;
  float ss = 0.f;
  for (int i = 0; i < 64; ++i){
    int p = i * 256 + tid;
    int y = p >> 7, x = p & 127;
    float a = 0.f;
    #pragma unroll
    for (int dy = 0; dy < 3; ++dy){
      int yy = y + dy - 1;
      if (yy < 0 || yy > 127) continue;
      #pragma unroll
      for (int dx = 0; dx < 3; ++dx){
        int xx = x + dx - 1;
        if (xx < 0 || xx > 127) continue;
        a += w[dy * 3 + dx] * b2f(ip[yy * 128 + xx]);
      }
    }
    op[p] = f2b(a);
    ss += a * a;
  }
  if (do_ssq){
    #pragma unroll
    for (int m = 32; m > 0; m >>= 1) ss += __shfl_xor(ss, m);
    if ((tid & 63) == 0) atomicAdd(&ssq[bc], ss);
  }
}

// ---------------------------------------------------------------------------
// K4: raw gram G[b][h][c][d] += sum_n q[c,n]*k[d,n], split-K (16 chunks),
// MFMA fragments straight from global (rows are K-contiguous), atomicAdd out.
// ---------------------------------------------------------------------------
__global__ void k_gram(const u16* __restrict__ q, const u16* __restrict__ k,
                       float* __restrict__ G)
{
  int tid = threadIdx.x;
  int chunk = blockIdx.x;                // 16 chunks of 1024 cols
  int h = blockIdx.y, b = blockIdx.z;
  int lane = tid & 63, w = tid >> 6;
  int quad = lane >> 4, r = lane & 15;
  int nb = chunk * 1024 + w * 256;
  const u16* qb = q + ((size_t)b * CCH + h * DHEAD) * HWSZ;
  const u16* kb = k + ((size_t)b * CCH + h * DHEAD) * HWSZ;
  f32x4 acc[3][3] = {};
  for (int s = 0; s < 8; ++s){
    int kk = nb + s * 32 + quad * 8;
    bf16x8 af[3], bfr[3];
    #pragma unroll
    for (int i = 0; i < 3; ++i){
      af[i]  = *(const bf16x8*)(qb + (size_t)(i * 16 + r) * HWSZ + kk);
      bfr[i] = *(const bf16x8*)(kb + (size_t)(i * 16 + r) * HWSZ + kk);
    }
    #pragma unroll
    for (int i = 0; i < 3; ++i)
      #pragma unroll
      for (int j = 0; j < 3; ++j)
        acc[i][j] = __builtin_amdgcn_mfma_f32_16x16x32_bf16(af[i], bfr[j], acc[i][j], 0, 0, 0);
  }
  float* gb = G + (size_t)(b * NHEAD + h) * (DHEAD * DHEAD);
  #pragma unroll
  for (int i = 0; i < 3; ++i)
    #pragma unroll
    for (int j = 0; j < 3; ++j)
      #pragma unroll
      for (int rg = 0; rg < 4; ++rg){
        int row = i * 16 + quad * 4 + rg;
        int col = j * 16 + r;
        atomicAdd(&gb[row * DHEAD + col], acc[i][j][rg]);
      }
}

// ---------------------------------------------------------------------------
// K5: fused (scale by 1/||q||,1/||k||,temp) -> softmax -> attn@V; writes
// attention output TRANSPOSED bf16 [b][n][192] (K-contiguous for proj GEMM).
// ---------------------------------------------------------------------------
__global__ void k_attnv(const float* __restrict__ G, const float* __restrict__ ssq_q,
                        const float* __restrict__ ssq_k, const float* __restrict__ temp,
                        const u16* __restrict__ v, u16* __restrict__ aot)
{
  __shared__ float at[DHEAD * 49];
  __shared__ float rqs[DHEAD], rks[DHEAD];
  int tid = threadIdx.x;
  int chunk = blockIdx.x;                // 64 chunks of 256 cols
  int h = blockIdx.y, b = blockIdx.z;
  const float* gb = G + (size_t)(b * NHEAD + h) * (DHEAD * DHEAD);
  #pragma unroll
  for (int i = 0; i < 9; ++i){
    int e = i * 256 + tid;
    int rw = e / DHEAD;
    at[rw * 49 + (e - rw * DHEAD)] = gb[e];
  }
  if (tid < DHEAD){
    float sq = sqrtf(ssq_q[b * CCH + h * DHEAD + tid]);
    float sk = sqrtf(ssq_k[b * CCH + h * DHEAD + tid]);
    rqs[tid] = 1.f / fmaxf(sq, 1e-12f);
    rks[tid] = 1.f / fmaxf(sk, 1e-12f);
  }
  __syncthreads();
  if (tid < DHEAD){
    float rq = rqs[tid] * temp[h];
    float mx = -1e30f;
    #pragma unroll
    for (int d = 0; d < DHEAD; ++d){
      float a = at[tid * 49 + d] * rq * rks[d];
      at[tid * 49 + d] = a;
      mx = fmaxf(mx, a);
    }
    float sum = 0.f;
    #pragma unroll
    for (int d = 0; d < DHEAD; ++d){
      float e = __expf(at[tid * 49 + d] - mx);
      at[tid * 49 + d] = e;
      sum += e;
    }
    float inv = 1.f / sum;
    #pragma unroll
    for (int d = 0; d < DHEAD; ++d) at[tid * 49 + d] *= inv;
  }
  __syncthreads();
  int n = chunk * 256 + tid;
  const u16* vb = v + ((size_t)b * CCH + h * DHEAD) * HWSZ + n;
  float o[DHEAD];
  #pragma unroll
  for (int cdx = 0; cdx < DHEAD; ++cdx) o[cdx] = 0.f;
  for (int d = 0; d < DHEAD; ++d){
    float vv = b2f(vb[(size_t)d * HWSZ]);
    #pragma unroll
    for (int cdx = 0; cdx < DHEAD; ++cdx)
      o[cdx] += at[cdx * 49 + d] * vv;
  }
  u16* ab = aot + ((size_t)b * HWSZ + n) * CCH + h * DHEAD;
  #pragma unroll
  for (int g = 0; g < 6; ++g){
    s16x8 pk;
    #pragma unroll
    for (int e = 0; e < 8; ++e) pk[e] = (short)f2b(o[g * 8 + e]);
    *(s16x8*)(&ab[g * 8]) = pk;
  }
}

// ---------------------------------------------------------------------------
extern "C" void kernel_launch(void* const* d_in, const int* in_sizes, int n_in,
                              void* d_out, int out_size, void* d_ws, size_t ws_size,
                              hipStream_t stream)
{
  const float* xx     = (const float*)d_in[0];
  const float* q_in   = (const float*)d_in[1];
  const float* ln_w   = (const float*)d_in[2];
  const float* ln_b   = (const float*)d_in[3];
  const float* w_q    = (const float*)d_in[4];
  const float* w_k    = (const float*)d_in[5];
  const float* w_v    = (const float*)d_in[6];
  const float* wd_q   = (const float*)d_in[7];
  const float* wd_k   = (const float*)d_in[8];
  const float* wd_v   = (const float*)d_in[9];
  const float* w_proj = (const float*)d_in[10];
  const float* temp   = (const float*)d_in[11];

  const size_t SZ = (size_t)NB * CCH * HWSZ;     // 25,165,824 elems
  u16* B1 = (u16*)d_ws;                          // xnT / qnT -> q_dw -> AOT
  u16* B2 = B1 + SZ;                             // kc -> v_dw
  u16* B3 = B2 + SZ;                             // qc -> k_dw
  float* G     = (float*)(B3 + SZ);              // [8][4][48][48]
  float* ssq_q = G + 32 * DHEAD * DHEAD;         // [8][192]
  float* ssq_k = ssq_q + NB * CCH;
  u16* outscratch = (u16*)d_out;                 // bf16 scratch inside f32 d_out

  hipMemsetAsync(G, 0, (size_t)(32 * DHEAD * DHEAD + 2 * NB * CCH) * sizeof(float), stream);

  dim3 gg(128, 3, NB);
  // x_n^T -> B1 ; k_conv -> B2 ; v_conv -> d_out (bf16 scratch) ; q_n^T -> B1 ; q_conv -> B3
  k_ln_t<<<NB * 256, 256, 0, stream>>>(xx, ln_w, ln_b, B1);
  k_gemm<0><<<gg, 256, 0, stream>>>(w_k, B1, B2, nullptr);
  k_gemm<0><<<gg, 256, 0, stream>>>(w_v, B1, outscratch, nullptr);
  k_ln_t<<<NB * 256, 256, 0, stream>>>(q_in, ln_w, ln_b, B1);
  k_gemm<0><<<gg, 256, 0, stream>>>(w_q, B1, B3, nullptr);
  // dwconv: q: B3->B1, k: B2->B3, v: d_out->B2  (+ row sumsq for q,k)
  k_dw<<<NB * CCH, 256, 0, stream>>>(B3, wd_q, B1, ssq_q, 1);
  k_dw<<<NB * CCH, 256, 0, stream>>>(B2, wd_k, B3, ssq_k, 1);
  k_dw<<<NB * CCH, 256, 0, stream>>>(outscratch, wd_v, B2, ssq_q, 0);
  // gram (q_dw=B1, k_dw=B3) -> G ; softmax+attn@V (v=B2) -> AOT=B1
  k_gram<<<dim3(16, NHEAD, NB), 256, 0, stream>>>(B1, B3, G);
  k_attnv<<<dim3(64, NHEAD, NB), 256, 0, stream>>>(G, ssq_q, ssq_k, temp, B2, B1);
  // proj + residual -> d_out (f32)
  k_gemm<1><<<gg, 256, 0, stream>>>(w_proj, B1, d_out, q_in);
}

// Round 4
// 670.921 us; speedup vs baseline: 1.6466x; 1.6466x over previous
//
#include <hip/hip_runtime.h>
#include <hip/hip_bf16.h>
#include <stdint.h>

#define HWSZ 16384
#define CCH 192
#define NB 8
#define NHEAD 4
#define DHEAD 48

typedef unsigned short u16;
typedef __bf16 bf16x8 __attribute__((ext_vector_type(8)));
typedef float f32x4 __attribute__((ext_vector_type(4)));
typedef short s16x8 __attribute__((ext_vector_type(8)));

__device__ __forceinline__ float b2f(u16 h){
  union { unsigned u; float f; } v; v.u = ((unsigned)h) << 16; return v.f;
}
__device__ __forceinline__ u16 f2b(float f){
  union { float f; unsigned u; } v; v.f = f;
  unsigned r = v.u + 0x7fffu + ((v.u >> 16) & 1u);
  return (u16)(r >> 16);
}

// ---------------------------------------------------------------------------
// K1: per-pixel LayerNorm over 192 channels (f32 in); writes normalized x
// TRANSPOSED as bf16 [b][hw][192] (K-contiguous rows for A*B^T MFMA GEMMs).
// ---------------------------------------------------------------------------
__global__ void k_ln_t(const float* __restrict__ x, const float* __restrict__ lnw,
                       const float* __restrict__ lnb, u16* __restrict__ out)
{
  __shared__ float xs[CCH * 65];
  __shared__ float mus[64], rstds[64];
  __shared__ float lw[CCH], lb[CCH];
  int tid = threadIdx.x;
  int bx  = blockIdx.x;
  int b    = bx >> 8;
  int tile = bx & 255;
  int p0   = tile * 64;
  if (tid < CCH){ lw[tid] = lnw[tid]; lb[tid] = lnb[tid]; }
  int pl = tid & 63, ch0 = tid >> 6;
  const float* xb = x + (size_t)b * CCH * HWSZ + p0 + pl;
  #pragma unroll
  for (int j = 0; j < 48; ++j){
    int c = ch0 + j * 4;
    xs[c * 65 + pl] = xb[(size_t)c * HWSZ];
  }
  __syncthreads();
  if (tid < 64){
    float s = 0.f, ss = 0.f;
    for (int c = 0; c < CCH; ++c){ float v = xs[c * 65 + tid]; s += v; ss += v * v; }
    float mu  = s * (1.f / CCH);
    float var = ss * (1.f / CCH) - mu * mu;
    mus[tid] = mu; rstds[tid] = rsqrtf(var + 1e-5f);
  }
  __syncthreads();
  u16* ob = out + ((size_t)b * HWSZ + p0) * CCH;
  for (int i = 0; i < 48; ++i){
    int e = i * 256 + tid;
    int p = e / CCH, c = e - p * CCH;
    float v = (xs[c * 65 + p] - mus[p]) * rstds[p] * lw[c] + lb[c];
    ob[e] = f2b(v);
  }
}

// ---------------------------------------------------------------------------
// K2: MFMA GEMM  Out[b][o][n] = sum_c A[o][c] * Bm[b][n][c]   (A*B^T)
// ---------------------------------------------------------------------------
template<int F32OUT>
__global__ __launch_bounds__(256, 2) void k_gemm(
    const float* __restrict__ A, const u16* __restrict__ Bm,
    void* __restrict__ Outv, const float* __restrict__ resid)
{
  __shared__ u16 lA[64 * 200];
  __shared__ u16 lB[128 * 200];
  int tid = threadIdx.x;
  int n0 = blockIdx.x * 128;
  int m0 = blockIdx.y * 64;
  int b  = blockIdx.z;
  {
    const float* ap = A + m0 * CCH;
    #pragma unroll
    for (int i = 0; i < 6; ++i){
      int off = (i * 256 + tid) * 8;
      float4 v0 = *(const float4*)(ap + off);
      float4 v1 = *(const float4*)(ap + off + 4);
      int row = off / CCH, col = off - row * CCH;
      s16x8 pk;
      pk[0] = (short)f2b(v0.x); pk[1] = (short)f2b(v0.y);
      pk[2] = (short)f2b(v0.z); pk[3] = (short)f2b(v0.w);
      pk[4] = (short)f2b(v1.x); pk[5] = (short)f2b(v1.y);
      pk[6] = (short)f2b(v1.z); pk[7] = (short)f2b(v1.w);
      *(s16x8*)(&lA[row * 200 + col]) = pk;
    }
  }
  {
    const u16* bp = Bm + ((size_t)b * HWSZ + n0) * CCH;
    #pragma unroll
    for (int i = 0; i < 12; ++i){
      int off = (i * 256 + tid) * 8;
      int4 v = *(const int4*)(bp + off);
      int row = off / CCH, col = off - row * CCH;
      *(int4*)(&lB[row * 200 + col]) = v;
    }
  }
  __syncthreads();
  int lane = tid & 63, wid = tid >> 6;
  int quad = lane >> 4, r = lane & 15;
  int wm = (wid >> 1) * 32, wn = (wid & 1) * 64;
  f32x4 acc[2][4] = {};
  #pragma unroll
  for (int k0 = 0; k0 < CCH; k0 += 32){
    bf16x8 af[2], bfr[4];
    #pragma unroll
    for (int i = 0; i < 2; ++i)
      af[i] = *(const bf16x8*)(&lA[(wm + i * 16 + r) * 200 + k0 + quad * 8]);
    #pragma unroll
    for (int j = 0; j < 4; ++j)
      bfr[j] = *(const bf16x8*)(&lB[(wn + j * 16 + r) * 200 + k0 + quad * 8]);
    #pragma unroll
    for (int i = 0; i < 2; ++i)
      #pragma unroll
      for (int j = 0; j < 4; ++j)
        acc[i][j] = __builtin_amdgcn_mfma_f32_16x16x32_bf16(af[i], bfr[j], acc[i][j], 0, 0, 0);
  }
  size_t obase = (size_t)b * CCH * HWSZ;
  #pragma unroll
  for (int i = 0; i < 2; ++i){
    #pragma unroll
    for (int rg = 0; rg < 4; ++rg){
      int o = m0 + wm + i * 16 + quad * 4 + rg;
      size_t rowb = obase + (size_t)o * HWSZ;
      #pragma unroll
      for (int j = 0; j < 4; ++j){
        int n = n0 + wn + j * 16 + r;
        float vv = acc[i][j][rg];
        if (F32OUT){
          ((float*)Outv)[rowb + n] = vv + resid[rowb + n];
        } else {
          ((u16*)Outv)[rowb + n] = f2b(vv);
        }
      }
    }
  }
}

// ---------------------------------------------------------------------------
// K3: merged depthwise 3x3 for q,k,v — one block = one full 128x128 plane,
// staged in LDS, computed IN-PLACE (8 px per thread, vectorized).
// blockIdx.y: 0=q (ssq_q), 1=k (ssq_k), 2=v (no ssq).
// ---------------------------------------------------------------------------
__global__ __launch_bounds__(256) void k_dw3(
    const float* __restrict__ wq, const float* __restrict__ wk,
    const float* __restrict__ wv,
    u16* __restrict__ bq, u16* __restrict__ bk, u16* __restrict__ bv,
    float* __restrict__ ssq_q, float* __restrict__ ssq_k)
{
  __shared__ u16 pln[HWSZ];             // 32 KB
  int tid = threadIdx.x;
  int bc  = blockIdx.x;                 // b*192 + c
  int z   = blockIdx.y;                 // 0=q 1=k 2=v
  int c   = bc % CCH;
  const float* wd = (z == 0) ? wq : (z == 1) ? wk : wv;
  u16* buf = (z == 0) ? bq : (z == 1) ? bk : bv;
  float w[9];
  #pragma unroll
  for (int t = 0; t < 9; ++t) w[t] = wd[c * 9 + t];
  u16* p = buf + (size_t)bc * HWSZ;
  // stage full plane into LDS (coalesced int4)
  {
    int4* lp = (int4*)pln;
    const int4* gp = (const int4*)p;
    #pragma unroll
    for (int i = 0; i < 8; ++i) lp[i * 256 + tid] = gp[i * 256 + tid];
  }
  __syncthreads();
  float ss = 0.f;
  #pragma unroll
  for (int i = 0; i < 8; ++i){
    int s  = i * 256 + tid;             // 2048 segments of 8 px
    int y  = s >> 4;
    int x0 = (s & 15) << 3;
    float acc[8] = {0.f,0.f,0.f,0.f,0.f,0.f,0.f,0.f};
    #pragma unroll
    for (int dy = 0; dy < 3; ++dy){
      int yy = y + dy - 1;
      if (yy < 0 || yy > 127) continue;
      int base = yy * 128 + x0;
      s16x8 cv = *(const s16x8*)(&pln[base]);
      float c8[8];
      #pragma unroll
      for (int j = 0; j < 8; ++j) c8[j] = b2f((u16)cv[j]);
      float lft = (x0 > 0)   ? b2f(pln[base - 1]) : 0.f;
      float rgt = (x0 < 120) ? b2f(pln[base + 8]) : 0.f;
      float wl = w[dy * 3], wc = w[dy * 3 + 1], wr = w[dy * 3 + 2];
      acc[0] += wl * lft + wc * c8[0] + wr * c8[1];
      #pragma unroll
      for (int j = 1; j < 7; ++j)
        acc[j] += wl * c8[j - 1] + wc * c8[j] + wr * c8[j + 1];
      acc[7] += wl * c8[6] + wc * c8[7] + wr * rgt;
    }
    s16x8 pk;
    #pragma unroll
    for (int j = 0; j < 8; ++j){
      pk[j] = (short)f2b(acc[j]);
      ss += acc[j] * acc[j];
    }
    *(s16x8*)(p + y * 128 + x0) = pk;   // in-place write (reads were from LDS)
  }
  if (z < 2){
    #pragma unroll
    for (int m = 32; m > 0; m >>= 1) ss += __shfl_xor(ss, m);
    if ((tid & 63) == 0) atomicAdd(&((z == 0) ? ssq_q : ssq_k)[bc], ss);
  }
}

// ---------------------------------------------------------------------------
// K4: raw gram G[b][h][c][d] += sum_n q[c,n]*k[d,n], split-K (16 chunks),
// MFMA fragments straight from global, atomicAdd out.
// ---------------------------------------------------------------------------
__global__ void k_gram(const u16* __restrict__ q, const u16* __restrict__ k,
                       float* __restrict__ G)
{
  int tid = threadIdx.x;
  int chunk = blockIdx.x;
  int h = blockIdx.y, b = blockIdx.z;
  int lane = tid & 63, w = tid >> 6;
  int quad = lane >> 4, r = lane & 15;
  int nb = chunk * 1024 + w * 256;
  const u16* qb = q + ((size_t)b * CCH + h * DHEAD) * HWSZ;
  const u16* kb = k + ((size_t)b * CCH + h * DHEAD) * HWSZ;
  f32x4 acc[3][3] = {};
  for (int s = 0; s < 8; ++s){
    int kk = nb + s * 32 + quad * 8;
    bf16x8 af[3], bfr[3];
    #pragma unroll
    for (int i = 0; i < 3; ++i){
      af[i]  = *(const bf16x8*)(qb + (size_t)(i * 16 + r) * HWSZ + kk);
      bfr[i] = *(const bf16x8*)(kb + (size_t)(i * 16 + r) * HWSZ + kk);
    }
    #pragma unroll
    for (int i = 0; i < 3; ++i)
      #pragma unroll
      for (int j = 0; j < 3; ++j)
        acc[i][j] = __builtin_amdgcn_mfma_f32_16x16x32_bf16(af[i], bfr[j], acc[i][j], 0, 0, 0);
  }
  float* gb = G + (size_t)(b * NHEAD + h) * (DHEAD * DHEAD);
  #pragma unroll
  for (int i = 0; i < 3; ++i)
    #pragma unroll
    for (int j = 0; j < 3; ++j)
      #pragma unroll
      for (int rg = 0; rg < 4; ++rg){
        int row = i * 16 + quad * 4 + rg;
        int col = j * 16 + r;
        atomicAdd(&gb[row * DHEAD + col], acc[i][j][rg]);
      }
}

// ---------------------------------------------------------------------------
// K5: fused (1/||q||,1/||k||,temp) -> softmax -> attn@V; writes attention
// output TRANSPOSED bf16 [b][n][192] (K-contiguous for proj GEMM).
// ---------------------------------------------------------------------------
__global__ void k_attnv(const float* __restrict__ G, const float* __restrict__ ssq_q,
                        const float* __restrict__ ssq_k, const float* __restrict__ temp,
                        const u16* __restrict__ v, u16* __restrict__ aot)
{
  __shared__ float at[DHEAD * 49];
  __shared__ float rqs[DHEAD], rks[DHEAD];
  int tid = threadIdx.x;
  int chunk = blockIdx.x;
  int h = blockIdx.y, b = blockIdx.z;
  const float* gb = G + (size_t)(b * NHEAD + h) * (DHEAD * DHEAD);
  #pragma unroll
  for (int i = 0; i < 9; ++i){
    int e = i * 256 + tid;
    int rw = e / DHEAD;
    at[rw * 49 + (e - rw * DHEAD)] = gb[e];
  }
  if (tid < DHEAD){
    float sq = sqrtf(ssq_q[b * CCH + h * DHEAD + tid]);
    float sk = sqrtf(ssq_k[b * CCH + h * DHEAD + tid]);
    rqs[tid] = 1.f / fmaxf(sq, 1e-12f);
    rks[tid] = 1.f / fmaxf(sk, 1e-12f);
  }
  __syncthreads();
  if (tid < DHEAD){
    float rq = rqs[tid] * temp[h];
    float mx = -1e30f;
    #pragma unroll
    for (int d = 0; d < DHEAD; ++d){
      float a = at[tid * 49 + d] * rq * rks[d];
      at[tid * 49 + d] = a;
      mx = fmaxf(mx, a);
    }
    float sum = 0.f;
    #pragma unroll
    for (int d = 0; d < DHEAD; ++d){
      float e = __expf(at[tid * 49 + d] - mx);
      at[tid * 49 + d] = e;
      sum += e;
    }
    float inv = 1.f / sum;
    #pragma unroll
    for (int d = 0; d < DHEAD; ++d) at[tid * 49 + d] *= inv;
  }
  __syncthreads();
  int n = chunk * 256 + tid;
  const u16* vb = v + ((size_t)b * CCH + h * DHEAD) * HWSZ + n;
  float o[DHEAD];
  #pragma unroll
  for (int cdx = 0; cdx < DHEAD; ++cdx) o[cdx] = 0.f;
  for (int d = 0; d < DHEAD; ++d){
    float vv = b2f(vb[(size_t)d * HWSZ]);
    #pragma unroll
    for (int cdx = 0; cdx < DHEAD; ++cdx)
      o[cdx] += at[cdx * 49 + d] * vv;
  }
  u16* ab = aot + ((size_t)b * HWSZ + n) * CCH + h * DHEAD;
  #pragma unroll
  for (int g = 0; g < 6; ++g){
    s16x8 pk;
    #pragma unroll
    for (int e = 0; e < 8; ++e) pk[e] = (short)f2b(o[g * 8 + e]);
    *(s16x8*)(&ab[g * 8]) = pk;
  }
}

// ---------------------------------------------------------------------------
extern "C" void kernel_launch(void* const* d_in, const int* in_sizes, int n_in,
                              void* d_out, int out_size, void* d_ws, size_t ws_size,
                              hipStream_t stream)
{
  const float* xx     = (const float*)d_in[0];
  const float* q_in   = (const float*)d_in[1];
  const float* ln_w   = (const float*)d_in[2];
  const float* ln_b   = (const float*)d_in[3];
  const float* w_q    = (const float*)d_in[4];
  const float* w_k    = (const float*)d_in[5];
  const float* w_v    = (const float*)d_in[6];
  const float* wd_q   = (const float*)d_in[7];
  const float* wd_k   = (const float*)d_in[8];
  const float* wd_v   = (const float*)d_in[9];
  const float* w_proj = (const float*)d_in[10];
  const float* temp   = (const float*)d_in[11];

  const size_t SZ = (size_t)NB * CCH * HWSZ;
  u16* B1 = (u16*)d_ws;                          // xnT / qnT -> AOT
  u16* B2 = B1 + SZ;                             // k_conv -> k_dw (in-place)
  u16* B3 = B2 + SZ;                             // q_conv -> q_dw (in-place)
  float* G     = (float*)(B3 + SZ);
  float* ssq_q = G + 32 * DHEAD * DHEAD;
  float* ssq_k = ssq_q + NB * CCH;
  u16* outscratch = (u16*)d_out;                 // v_conv -> v_dw (in-place)

  hipMemsetAsync(G, 0, (size_t)(32 * DHEAD * DHEAD + 2 * NB * CCH) * sizeof(float), stream);

  dim3 gg(128, 3, NB);
  k_ln_t<<<NB * 256, 256, 0, stream>>>(xx, ln_w, ln_b, B1);
  k_gemm<0><<<gg, 256, 0, stream>>>(w_k, B1, B2, nullptr);
  k_gemm<0><<<gg, 256, 0, stream>>>(w_v, B1, outscratch, nullptr);
  k_ln_t<<<NB * 256, 256, 0, stream>>>(q_in, ln_w, ln_b, B1);
  k_gemm<0><<<gg, 256, 0, stream>>>(w_q, B1, B3, nullptr);
  // merged depthwise: q in B3, k in B2, v in outscratch — all in-place
  k_dw3<<<dim3(NB * CCH, 3), 256, 0, stream>>>(wd_q, wd_k, wd_v,
                                               B3, B2, outscratch, ssq_q, ssq_k);
  // gram (q_dw=B3, k_dw=B2) -> G ; softmax+attn@V (v=outscratch) -> AOT=B1
  k_gram<<<dim3(16, NHEAD, NB), 256, 0, stream>>>(B3, B2, G);
  k_attnv<<<dim3(64, NHEAD, NB), 256, 0, stream>>>(G, ssq_q, ssq_k, temp, outscratch, B1);
  // proj + residual -> d_out (f32)
  k_gemm<1><<<gg, 256, 0, stream>>>(w_proj, B1, d_out, q_in);
}